// Round 7
// baseline (86.944 us; speedup 1.0000x reference)
//
#include <hip/hip_runtime.h>

#define NSAMP 64
#define PER_SAMPLE (512 * 512)                 // 262144 elements per sample
#define BLOCKS_PER_SAMPLE 32
#define NBLOCKS (NSAMP * BLOCKS_PER_SAMPLE)    // 2048 blocks
#define THREADS 256
#define TOPK 42
#define LOG2_CLAMP -144.26950408889634f        // -100 / ln(2)
#define LN2F 0.69314718055994531f

__device__ __forceinline__ void issue_load(float4& dst, const float4* addr) {
    asm volatile("global_load_dwordx4 %0, %1, off" : "=v"(dst) : "v"(addr));
}

// Fused: per-block partial BCE sum (log2 domain, 16-deep forced MLP), then
// last-block-done gather + rank-select. Release-only per block; the single
// last block pays the one acquire.
__global__ __launch_bounds__(THREADS) void ohem_fused(
    const float* __restrict__ preds,
    const float* __restrict__ targets,
    float* __restrict__ partials,            // [sample][chunk], NBLOCKS floats
    unsigned int* __restrict__ counter,      // zeroed on-stream pre-launch
    float* __restrict__ out) {
    const int vec_per_sample = PER_SAMPLE / 4;                      // 65536
    const int vec_per_block  = vec_per_sample / BLOCKS_PER_SAMPLE;  // 2048 float4
    const int sample = blockIdx.x >> 5;
    const int chunk  = blockIdx.x & 31;
    const size_t base = (size_t)sample * vec_per_sample + (size_t)chunk * vec_per_block;

    const float4* __restrict__ pp = (const float4*)preds   + base + threadIdx.x;
    const float4* __restrict__ tt = (const float4*)targets + base + threadIdx.x;

    float4 p[8], t[8];
    #pragma unroll
    for (int j = 0; j < 8; ++j) {
        issue_load(p[j], pp + j * THREADS);
        issue_load(t[j], tt + j * THREADS);
    }

    float acc = 0.0f;   // +(t*log2 p + (1-t)*log2(1-p)); negate*ln2 at end

    asm volatile("s_waitcnt vmcnt(8)" ::: "memory");
    __builtin_amdgcn_sched_barrier(0);
    #pragma unroll
    for (int j = 0; j < 4; ++j) {
        float lpx = fmaxf(__log2f(p[j].x), LOG2_CLAMP), l1x = fmaxf(__log2f(1.0f - p[j].x), LOG2_CLAMP);
        float lpy = fmaxf(__log2f(p[j].y), LOG2_CLAMP), l1y = fmaxf(__log2f(1.0f - p[j].y), LOG2_CLAMP);
        float lpz = fmaxf(__log2f(p[j].z), LOG2_CLAMP), l1z = fmaxf(__log2f(1.0f - p[j].z), LOG2_CLAMP);
        float lpw = fmaxf(__log2f(p[j].w), LOG2_CLAMP), l1w = fmaxf(__log2f(1.0f - p[j].w), LOG2_CLAMP);
        acc += l1x;  acc = fmaf(t[j].x, lpx - l1x, acc);
        acc += l1y;  acc = fmaf(t[j].y, lpy - l1y, acc);
        acc += l1z;  acc = fmaf(t[j].z, lpz - l1z, acc);
        acc += l1w;  acc = fmaf(t[j].w, lpw - l1w, acc);
    }

    asm volatile("s_waitcnt vmcnt(0)" ::: "memory");
    __builtin_amdgcn_sched_barrier(0);
    #pragma unroll
    for (int j = 4; j < 8; ++j) {
        float lpx = fmaxf(__log2f(p[j].x), LOG2_CLAMP), l1x = fmaxf(__log2f(1.0f - p[j].x), LOG2_CLAMP);
        float lpy = fmaxf(__log2f(p[j].y), LOG2_CLAMP), l1y = fmaxf(__log2f(1.0f - p[j].y), LOG2_CLAMP);
        float lpz = fmaxf(__log2f(p[j].z), LOG2_CLAMP), l1z = fmaxf(__log2f(1.0f - p[j].z), LOG2_CLAMP);
        float lpw = fmaxf(__log2f(p[j].w), LOG2_CLAMP), l1w = fmaxf(__log2f(1.0f - p[j].w), LOG2_CLAMP);
        acc += l1x;  acc = fmaf(t[j].x, lpx - l1x, acc);
        acc += l1y;  acc = fmaf(t[j].y, lpy - l1y, acc);
        acc += l1z;  acc = fmaf(t[j].z, lpz - l1z, acc);
        acc += l1w;  acc = fmaf(t[j].w, lpw - l1w, acc);
    }

    // wave (64-lane) butterfly reduction
    #pragma unroll
    for (int off = 32; off > 0; off >>= 1) acc += __shfl_down(acc, off, 64);

    __shared__ float smem[THREADS / 64];
    __shared__ int is_last;
    const int lane = threadIdx.x & 63;
    const int wid  = threadIdx.x >> 6;
    if (lane == 0) smem[wid] = acc;
    __syncthreads();
    if (threadIdx.x == 0) {
        float tot = 0.0f;
        #pragma unroll
        for (int w = 0; w < THREADS / 64; ++w) tot += smem[w];
        partials[blockIdx.x] = -tot * LN2F;        // plain store
        // RELEASE only: waitcnt + L2 writeback (nearly nothing dirty).
        // No acquire here -- that was R4's 2048x L2-invalidate disaster.
        unsigned int old = __hip_atomic_fetch_add(counter, 1u,
                           __ATOMIC_RELEASE, __HIP_MEMORY_SCOPE_AGENT);
        is_last = (old == NBLOCKS - 1);
    }
    __syncthreads();

    if (is_last) {
        // Exactly ONE block pays the acquire (L1/L2 invalidate) so its plain
        // loads below observe every block's released partial.
        __builtin_amdgcn_fence(__ATOMIC_ACQUIRE, "agent");

        __shared__ float quarter[THREADS];
        __shared__ float vals[NSAMP];
        const int tid = threadIdx.x;
        const int s = tid >> 2;            // sample 0..63
        const int q = tid & 3;             // quarter 0..3
        float sum8 = 0.0f;
        #pragma unroll
        for (int j = 0; j < 8; ++j)
            sum8 += partials[s * BLOCKS_PER_SAMPLE + q * 8 + j];
        quarter[tid] = sum8;
        __syncthreads();
        if (tid < NSAMP) {
            float sv = quarter[4 * tid] + quarter[4 * tid + 1]
                     + quarter[4 * tid + 2] + quarter[4 * tid + 3];
            vals[tid] = sv * (1.0f / (float)PER_SAMPLE);
        }
        __syncthreads();
        if (tid < NSAMP) {
            const float loss = vals[tid];
            // Descending stable rank: exactly TOPK entries get rank < TOPK.
            int rank = 0;
            for (int j = 0; j < NSAMP; ++j) {
                float v = vals[j];
                rank += (v > loss) || (v == loss && j < tid);
            }
            float contrib = (rank < TOPK) ? loss : 0.0f;
            #pragma unroll
            for (int off = 32; off > 0; off >>= 1)
                contrib += __shfl_down(contrib, off, 64);
            if (tid == 0) out[0] = contrib * (1.0f / (float)TOPK);
        }
    }
}

extern "C" void kernel_launch(void* const* d_in, const int* in_sizes, int n_in,
                              void* d_out, int out_size, void* d_ws, size_t ws_size,
                              hipStream_t stream) {
    const float* preds   = (const float*)d_in[0];
    const float* targets = (const float*)d_in[1];
    float* out      = (float*)d_out;
    float* partials = (float*)d_ws;                       // 8 KB
    unsigned int* counter = (unsigned int*)((char*)d_ws + NBLOCKS * sizeof(float));

    (void)hipMemsetAsync(counter, 0, sizeof(unsigned int), stream);
    ohem_fused<<<NBLOCKS, THREADS, 0, stream>>>(preds, targets, partials, counter, out);
}

// Round 8
// 44.118 us; speedup vs baseline: 1.9707x; 1.9707x over previous
//
#include <hip/hip_runtime.h>

#define NSAMP 64
#define PER_SAMPLE (512 * 512)                 // 262144 elements per sample
#define BLOCKS_PER_SAMPLE 32
#define NBLOCKS (NSAMP * BLOCKS_PER_SAMPLE)    // 2048 blocks
#define THREADS 256
#define TOPK 42
#define LOG2_CLAMP -144.26950408889634f        // -100 / ln(2)
#define LN2F 0.69314718055994531f

__device__ __forceinline__ void issue_load(float4& dst, const float4* addr) {
    asm volatile("global_load_dwordx4 %0, %1, off" : "=v"(dst) : "v"(addr));
}

// Fused: per-block partial BCE sum (log2 domain, 16-deep forced MLP), then
// last-block-done gather + rank-select.
// NO fences anywhere: partials travel via relaxed agent-scope atomics
// (HW-coherent, cache-bypassing); completion is ordered by a manual
// s_waitcnt vmcnt(0) before the relaxed counter bump. R4/R7 showed that
// release/acquire fences (buffer_wbl2/buffer_inv) cost 5x here.
__global__ __launch_bounds__(THREADS) void ohem_fused(
    const float* __restrict__ preds,
    const float* __restrict__ targets,
    float* __restrict__ partials,            // NBLOCKS floats, [sample][chunk]
    unsigned int* __restrict__ counter,      // zeroed on-stream pre-launch
    float* __restrict__ out) {
    const int vec_per_sample = PER_SAMPLE / 4;                      // 65536
    const int vec_per_block  = vec_per_sample / BLOCKS_PER_SAMPLE;  // 2048 float4
    const int sample = blockIdx.x >> 5;
    const int chunk  = blockIdx.x & 31;
    const size_t base = (size_t)sample * vec_per_sample + (size_t)chunk * vec_per_block;

    const float4* __restrict__ pp = (const float4*)preds   + base + threadIdx.x;
    const float4* __restrict__ tt = (const float4*)targets + base + threadIdx.x;

    float4 p[8], t[8];
    #pragma unroll
    for (int j = 0; j < 8; ++j) {
        issue_load(p[j], pp + j * THREADS);
        issue_load(t[j], tt + j * THREADS);
    }

    float acc = 0.0f;   // +(t*log2 p + (1-t)*log2(1-p)); negate*ln2 at end

    asm volatile("s_waitcnt vmcnt(8)" ::: "memory");
    __builtin_amdgcn_sched_barrier(0);
    #pragma unroll
    for (int j = 0; j < 4; ++j) {
        float lpx = fmaxf(__log2f(p[j].x), LOG2_CLAMP), l1x = fmaxf(__log2f(1.0f - p[j].x), LOG2_CLAMP);
        float lpy = fmaxf(__log2f(p[j].y), LOG2_CLAMP), l1y = fmaxf(__log2f(1.0f - p[j].y), LOG2_CLAMP);
        float lpz = fmaxf(__log2f(p[j].z), LOG2_CLAMP), l1z = fmaxf(__log2f(1.0f - p[j].z), LOG2_CLAMP);
        float lpw = fmaxf(__log2f(p[j].w), LOG2_CLAMP), l1w = fmaxf(__log2f(1.0f - p[j].w), LOG2_CLAMP);
        acc += l1x;  acc = fmaf(t[j].x, lpx - l1x, acc);
        acc += l1y;  acc = fmaf(t[j].y, lpy - l1y, acc);
        acc += l1z;  acc = fmaf(t[j].z, lpz - l1z, acc);
        acc += l1w;  acc = fmaf(t[j].w, lpw - l1w, acc);
    }

    asm volatile("s_waitcnt vmcnt(0)" ::: "memory");
    __builtin_amdgcn_sched_barrier(0);
    #pragma unroll
    for (int j = 4; j < 8; ++j) {
        float lpx = fmaxf(__log2f(p[j].x), LOG2_CLAMP), l1x = fmaxf(__log2f(1.0f - p[j].x), LOG2_CLAMP);
        float lpy = fmaxf(__log2f(p[j].y), LOG2_CLAMP), l1y = fmaxf(__log2f(1.0f - p[j].y), LOG2_CLAMP);
        float lpz = fmaxf(__log2f(p[j].z), LOG2_CLAMP), l1z = fmaxf(__log2f(1.0f - p[j].z), LOG2_CLAMP);
        float lpw = fmaxf(__log2f(p[j].w), LOG2_CLAMP), l1w = fmaxf(__log2f(1.0f - p[j].w), LOG2_CLAMP);
        acc += l1x;  acc = fmaf(t[j].x, lpx - l1x, acc);
        acc += l1y;  acc = fmaf(t[j].y, lpy - l1y, acc);
        acc += l1z;  acc = fmaf(t[j].z, lpz - l1z, acc);
        acc += l1w;  acc = fmaf(t[j].w, lpw - l1w, acc);
    }

    // wave (64-lane) butterfly reduction
    #pragma unroll
    for (int off = 32; off > 0; off >>= 1) acc += __shfl_down(acc, off, 64);

    __shared__ float smem[THREADS / 64];
    __shared__ int is_last;
    const int lane = threadIdx.x & 63;
    const int wid  = threadIdx.x >> 6;
    if (lane == 0) smem[wid] = acc;
    __syncthreads();
    if (threadIdx.x == 0) {
        float tot = 0.0f;
        #pragma unroll
        for (int w = 0; w < THREADS / 64; ++w) tot += smem[w];
        // Cache-bypassing coherent store of the partial (no fence).
        __hip_atomic_store(&partials[blockIdx.x], -tot * LN2F,
                           __ATOMIC_RELAXED, __HIP_MEMORY_SCOPE_AGENT);
        // Manual "release": wait for THAT store to reach the coherence
        // point, then bump the counter. No cache maintenance emitted.
        asm volatile("s_waitcnt vmcnt(0)" ::: "memory");
        unsigned int old = __hip_atomic_fetch_add(counter, 1u,
                           __ATOMIC_RELAXED, __HIP_MEMORY_SCOPE_AGENT);
        is_last = (old == NBLOCKS - 1);
    }
    __syncthreads();

    if (is_last) {
        // Gather via relaxed agent-scope atomic loads: they bypass the
        // (possibly stale) non-coherent caches, so no acquire is needed.
        __shared__ float quarter[THREADS];
        __shared__ float vals[NSAMP];
        const int tid = threadIdx.x;
        const int s = tid >> 2;            // sample 0..63
        const int q = tid & 3;             // quarter 0..3
        float sum8 = 0.0f;
        #pragma unroll
        for (int j = 0; j < 8; ++j)
            sum8 += __hip_atomic_load(&partials[s * BLOCKS_PER_SAMPLE + q * 8 + j],
                                      __ATOMIC_RELAXED, __HIP_MEMORY_SCOPE_AGENT);
        quarter[tid] = sum8;
        __syncthreads();
        if (tid < NSAMP) {
            float sv = quarter[4 * tid] + quarter[4 * tid + 1]
                     + quarter[4 * tid + 2] + quarter[4 * tid + 3];
            vals[tid] = sv * (1.0f / (float)PER_SAMPLE);
        }
        __syncthreads();
        if (tid < NSAMP) {
            const float loss = vals[tid];
            // Descending stable rank: exactly TOPK entries get rank < TOPK.
            int rank = 0;
            for (int j = 0; j < NSAMP; ++j) {
                float v = vals[j];
                rank += (v > loss) || (v == loss && j < tid);
            }
            float contrib = (rank < TOPK) ? loss : 0.0f;
            #pragma unroll
            for (int off = 32; off > 0; off >>= 1)
                contrib += __shfl_down(contrib, off, 64);
            if (tid == 0) out[0] = contrib * (1.0f / (float)TOPK);
        }
    }
}

extern "C" void kernel_launch(void* const* d_in, const int* in_sizes, int n_in,
                              void* d_out, int out_size, void* d_ws, size_t ws_size,
                              hipStream_t stream) {
    const float* preds   = (const float*)d_in[0];
    const float* targets = (const float*)d_in[1];
    float* out      = (float*)d_out;
    float* partials = (float*)d_ws;                       // 8 KB
    unsigned int* counter = (unsigned int*)((char*)d_ws + NBLOCKS * sizeof(float));

    (void)hipMemsetAsync(counter, 0, sizeof(unsigned int), stream);
    ohem_fused<<<NBLOCKS, THREADS, 0, stream>>>(preds, targets, partials, counter, out);
}

// Round 9
// 26.994 us; speedup vs baseline: 3.2209x; 1.6344x over previous
//
#include <hip/hip_runtime.h>

#define NSAMP 64
#define PER_SAMPLE (512 * 512)                 // 262144 elements per sample
#define BLOCKS_PER_SAMPLE 32
#define NBLOCKS (NSAMP * BLOCKS_PER_SAMPLE)    // 2048 blocks
#define THREADS 256
#define TOPK 42
#define LOG2_CLAMP -144.26950408889634f        // -100 / ln(2)
#define LN2F 0.69314718055994531f

__device__ __forceinline__ void issue_load(float4& dst, const float4* addr) {
    asm volatile("global_load_dwordx4 %0, %1, off" : "=v"(dst) : "v"(addr));
}

// Kernel 1: per-block partial BCE sums (log2 domain), forced 16-deep MLP.
// Each block owns a contiguous 8192-element chunk of one sample.
// (R5-proven body: ~22-23 us in replay = ~92% of achievable HBM ceiling.)
__global__ __launch_bounds__(THREADS) void bce_partial(
    const float* __restrict__ preds,
    const float* __restrict__ targets,
    float* __restrict__ partials) {
    const int vec_per_sample = PER_SAMPLE / 4;                      // 65536
    const int vec_per_block  = vec_per_sample / BLOCKS_PER_SAMPLE;  // 2048 float4
    const int sample = blockIdx.x >> 5;
    const int chunk  = blockIdx.x & 31;
    const size_t base = (size_t)sample * vec_per_sample + (size_t)chunk * vec_per_block;

    const float4* __restrict__ pp = (const float4*)preds   + base + threadIdx.x;
    const float4* __restrict__ tt = (const float4*)targets + base + threadIdx.x;

    float4 p[8], t[8];
    #pragma unroll
    for (int j = 0; j < 8; ++j) {
        issue_load(p[j], pp + j * THREADS);
        issue_load(t[j], tt + j * THREADS);
    }

    float acc = 0.0f;   // +(t*log2 p + (1-t)*log2(1-p)); negate*ln2 at end

    asm volatile("s_waitcnt vmcnt(8)" ::: "memory");
    __builtin_amdgcn_sched_barrier(0);
    #pragma unroll
    for (int j = 0; j < 4; ++j) {
        float lpx = fmaxf(__log2f(p[j].x), LOG2_CLAMP), l1x = fmaxf(__log2f(1.0f - p[j].x), LOG2_CLAMP);
        float lpy = fmaxf(__log2f(p[j].y), LOG2_CLAMP), l1y = fmaxf(__log2f(1.0f - p[j].y), LOG2_CLAMP);
        float lpz = fmaxf(__log2f(p[j].z), LOG2_CLAMP), l1z = fmaxf(__log2f(1.0f - p[j].z), LOG2_CLAMP);
        float lpw = fmaxf(__log2f(p[j].w), LOG2_CLAMP), l1w = fmaxf(__log2f(1.0f - p[j].w), LOG2_CLAMP);
        acc += l1x;  acc = fmaf(t[j].x, lpx - l1x, acc);
        acc += l1y;  acc = fmaf(t[j].y, lpy - l1y, acc);
        acc += l1z;  acc = fmaf(t[j].z, lpz - l1z, acc);
        acc += l1w;  acc = fmaf(t[j].w, lpw - l1w, acc);
    }

    asm volatile("s_waitcnt vmcnt(0)" ::: "memory");
    __builtin_amdgcn_sched_barrier(0);
    #pragma unroll
    for (int j = 4; j < 8; ++j) {
        float lpx = fmaxf(__log2f(p[j].x), LOG2_CLAMP), l1x = fmaxf(__log2f(1.0f - p[j].x), LOG2_CLAMP);
        float lpy = fmaxf(__log2f(p[j].y), LOG2_CLAMP), l1y = fmaxf(__log2f(1.0f - p[j].y), LOG2_CLAMP);
        float lpz = fmaxf(__log2f(p[j].z), LOG2_CLAMP), l1z = fmaxf(__log2f(1.0f - p[j].z), LOG2_CLAMP);
        float lpw = fmaxf(__log2f(p[j].w), LOG2_CLAMP), l1w = fmaxf(__log2f(1.0f - p[j].w), LOG2_CLAMP);
        acc += l1x;  acc = fmaf(t[j].x, lpx - l1x, acc);
        acc += l1y;  acc = fmaf(t[j].y, lpy - l1y, acc);
        acc += l1z;  acc = fmaf(t[j].z, lpz - l1z, acc);
        acc += l1w;  acc = fmaf(t[j].w, lpw - l1w, acc);
    }

    // wave (64-lane) butterfly reduction
    #pragma unroll
    for (int off = 32; off > 0; off >>= 1) acc += __shfl_down(acc, off, 64);

    __shared__ float smem[THREADS / 64];
    const int lane = threadIdx.x & 63;
    const int wid  = threadIdx.x >> 6;
    if (lane == 0) smem[wid] = acc;
    __syncthreads();
    if (threadIdx.x == 0) {
        float tot = 0.0f;
        #pragma unroll
        for (int w = 0; w < THREADS / 64; ++w) tot += smem[w];
        partials[blockIdx.x] = -tot * LN2F;   // back to natural-log domain
    }
}

// Kernel 2: one 256-thread block. Parallel quarter-sum gather (4 threads per
// sample, 8 partials each -- R8-verified pattern), per-sample mean, stable
// O(64^2) rank to pick the 42 largest, mean.
__global__ __launch_bounds__(THREADS) void topk_mean(
    const float* __restrict__ partials,
    float* __restrict__ out) {
    __shared__ float quarter[THREADS];
    __shared__ float vals[NSAMP];
    const int tid = threadIdx.x;
    const int s = tid >> 2;            // sample 0..63
    const int q = tid & 3;             // quarter 0..3
    float sum8 = 0.0f;
    #pragma unroll
    for (int j = 0; j < 8; ++j)
        sum8 += partials[s * BLOCKS_PER_SAMPLE + q * 8 + j];
    quarter[tid] = sum8;
    __syncthreads();
    if (tid < NSAMP) {
        float sv = quarter[4 * tid] + quarter[4 * tid + 1]
                 + quarter[4 * tid + 2] + quarter[4 * tid + 3];
        vals[tid] = sv * (1.0f / (float)PER_SAMPLE);
    }
    __syncthreads();
    if (tid < NSAMP) {
        const float loss = vals[tid];
        // Descending stable rank: exactly TOPK entries get rank < TOPK.
        int rank = 0;
        for (int j = 0; j < NSAMP; ++j) {
            float v = vals[j];
            rank += (v > loss) || (v == loss && j < tid);
        }
        float contrib = (rank < TOPK) ? loss : 0.0f;
        #pragma unroll
        for (int off = 32; off > 0; off >>= 1)
            contrib += __shfl_down(contrib, off, 64);
        if (tid == 0) out[0] = contrib * (1.0f / (float)TOPK);
    }
}

extern "C" void kernel_launch(void* const* d_in, const int* in_sizes, int n_in,
                              void* d_out, int out_size, void* d_ws, size_t ws_size,
                              hipStream_t stream) {
    const float* preds   = (const float*)d_in[0];
    const float* targets = (const float*)d_in[1];
    float* out      = (float*)d_out;
    float* partials = (float*)d_ws;   // NBLOCKS floats = 8 KB

    bce_partial<<<NBLOCKS, THREADS, 0, stream>>>(preds, targets, partials);
    topk_mean<<<1, THREADS, 0, stream>>>(partials, out);
}